// Round 4
// baseline (73.040 us; speedup 1.0000x reference)
//
#include <hip/hip_runtime.h>

// B-spline (piecewise-linear) activation, NCHW fp32.
// N=64, C=256, H=W=56, SIZE=51 knots, GRID=0.1.
// Block = 8 planes of ONE channel (grid = 2048 = 8 n-chunks x 256 channels):
//   - coeff table staged to LDS once per block (amortized 8x)
//   - register double-buffer: plane i+1 loads issued before plane i compute
//   - plane-0 loads issued BEFORE staging+barrier (hide coeff fetch)
// LDS holds 50 (c[i], c[i+1]) pairs -> one ds_read_b64 per element.
// Nontemporal loads/stores: zero reuse on either stream.

typedef float f32x4 __attribute__((ext_vector_type(4)));

constexpr int C_CH  = 256;
constexpr int KSIZE = 51;
constexpr int HW    = 56 * 56;       // 3136
constexpr int HW4   = HW / 4;        // 784 = 3*256 + 16
constexpr int PPB   = 8;             // planes per block (N=64 divisible)

__device__ __forceinline__ f32x4 bspline4(f32x4 v, const float2* sc, int bias) {
    f32x4 r;
    #pragma unroll
    for (int k = 0; k < 4; ++k) {
        float xe = v[k];
        // float32(-0.1*25) = -2.5f, float32(0.1*24) = 2.4f
        float xc = fminf(fmaxf(xe, -2.5f), 2.4f);
        float fl = floorf(xc * 10.0f);        // left-knot offset
        float fr = xe * 10.0f - fl;           // frac uses UNclamped x
        float2 cc = sc[(int)fl + bias];       // (c0, c1): one ds_read_b64
        r[k] = cc.y * fr + cc.x * (1.0f - fr);
    }
    return r;
}

__global__ __launch_bounds__(256)
void bspline_act_kernel(const float* __restrict__ x,
                        const float* __restrict__ coeff,
                        const int*   __restrict__ zk,
                        float*       __restrict__ out)
{
    const int bid = blockIdx.x;
    const int c   = bid & (C_CH - 1);           // channel
    const int n0  = (bid >> 8) * PPB;           // first batch index
    const int tid = threadIdx.x;

    const size_t  base    = ((size_t)n0 * C_CH + c) * HW;
    const size_t  vstride = (size_t)C_CH * HW / 4;   // f32x4 stride between n's
    const f32x4* __restrict__ xv = (const f32x4*)(x + base);
    f32x4*       __restrict__ ov = (f32x4*)(out + base);

    const bool tail = tid < (HW4 - 768);        // 16-f32x4 tail

    // Plane 0 loads in flight before the staging barrier.
    f32x4 a0 = __builtin_nontemporal_load(xv + tid);
    f32x4 a1 = __builtin_nontemporal_load(xv + tid + 256);
    f32x4 a2 = __builtin_nontemporal_load(xv + tid + 512);
    f32x4 a3 = {0,0,0,0};
    if (tail) a3 = __builtin_nontemporal_load(xv + tid + 768);

    __shared__ float2 sc[KSIZE - 1];            // sc[i] = (coeff[i], coeff[i+1])
    if (tid < KSIZE - 1) {
        float va = coeff[c * KSIZE + tid];
        float vb = coeff[c * KSIZE + tid + 1];
        sc[tid] = make_float2(va, vb);
    }
    const int bias = zk[c] - c * KSIZE;         // == 25
    __syncthreads();

    #pragma unroll
    for (int pl = 0; pl < PPB; ++pl) {
        f32x4 b0, b1, b2, b3;
        if (pl + 1 < PPB) {                     // issue next plane's loads first
            const f32x4* xn = xv + (size_t)(pl + 1) * vstride;
            b0 = __builtin_nontemporal_load(xn + tid);
            b1 = __builtin_nontemporal_load(xn + tid + 256);
            b2 = __builtin_nontemporal_load(xn + tid + 512);
            if (tail) b3 = __builtin_nontemporal_load(xn + tid + 768);
        }
        f32x4* oc = ov + (size_t)pl * vstride;
        __builtin_nontemporal_store(bspline4(a0, sc, bias), oc + tid);
        __builtin_nontemporal_store(bspline4(a1, sc, bias), oc + tid + 256);
        __builtin_nontemporal_store(bspline4(a2, sc, bias), oc + tid + 512);
        if (tail)
            __builtin_nontemporal_store(bspline4(a3, sc, bias), oc + tid + 768);
        if (pl + 1 < PPB) {                     // register rename under unroll
            a0 = b0; a1 = b1; a2 = b2;
            if (tail) a3 = b3;
        }
    }
}

extern "C" void kernel_launch(void* const* d_in, const int* in_sizes, int n_in,
                              void* d_out, int out_size, void* d_ws, size_t ws_size,
                              hipStream_t stream) {
    const float* x     = (const float*)d_in[0];
    const float* coeff = (const float*)d_in[1];
    const int*   zk    = (const int*)d_in[2];
    float*       out   = (float*)d_out;

    const int n_planes = out_size / HW;          // N*C = 16384
    const int blocks   = n_planes / PPB;         // 2048
    bspline_act_kernel<<<blocks, 256, 0, stream>>>(x, coeff, zk, out);
}

// Round 5
// 68.839 us; speedup vs baseline: 1.0610x; 1.0610x over previous
//
#include <hip/hip_runtime.h>

// B-spline (piecewise-linear) activation, NCHW fp32.
// N=64, C=256, H=W=56, SIZE=51 knots per channel, GRID=0.1.
// One block per (n,c) plane; channel is block-uniform.
// LDS holds the 50 (c[i], c[i+1]) pairs -> single ds_read_b64 per element.
// All global loads issued up-front (3 full + predicated tail) for MLP;
// nontemporal loads/stores since neither stream has reuse.
// NOTE (R4 post-mortem): PPB=8 multi-plane blocks regressed to 73 us —
// 2048 blocks lose dynamic backfill; prologue was already latency-hidden.
// This 16384-block version measured 68.9 us = 94.9% of float4-copy ceiling.

typedef float f32x4 __attribute__((ext_vector_type(4)));

constexpr int C_CH  = 256;
constexpr int KSIZE = 51;
constexpr int HW    = 56 * 56;   // 3136
constexpr int HW4   = HW / 4;    // 784 float4 per plane (= 3*256 + 16)

__device__ __forceinline__ f32x4 bspline4(f32x4 v, const float2* sc, int bias) {
    f32x4 r;
    #pragma unroll
    for (int k = 0; k < 4; ++k) {
        float xe = v[k];
        // float32(-0.1*25) = -2.5f, float32(0.1*24) = 2.4f
        float xc = fminf(fmaxf(xe, -2.5f), 2.4f);
        float fl = floorf(xc * 10.0f);        // left-knot offset
        float fr = xe * 10.0f - fl;           // frac uses UNclamped x
        float2 cc = sc[(int)fl + bias];       // (c0, c1), one ds_read_b64
        r[k] = cc.y * fr + cc.x * (1.0f - fr);
    }
    return r;
}

__global__ __launch_bounds__(256)
void bspline_act_kernel(const float* __restrict__ x,
                        const float* __restrict__ coeff,
                        const int*   __restrict__ zk,
                        float*       __restrict__ out)
{
    const int p   = blockIdx.x;          // plane index in [0, N*C)
    const int c   = p & (C_CH - 1);      // channel (C_CH is power of two)
    const int tid = threadIdx.x;

    __shared__ float2 sc[KSIZE - 1];     // sc[i] = (coeff[i], coeff[i+1])
    if (tid < KSIZE - 1) {
        float a = coeff[c * KSIZE + tid];
        float b = coeff[c * KSIZE + tid + 1];
        sc[tid] = make_float2(a, b);
    }
    const int bias = zk[c] - c * KSIZE;  // == half_knots (25)
    __syncthreads();

    const f32x4* __restrict__ xv = (const f32x4*)(x + (size_t)p * HW);
    f32x4*       __restrict__ ov = (f32x4*)(out + (size_t)p * HW);

    // Issue all loads before any dependent compute: 3-4 in flight per thread.
    f32x4 v0 = __builtin_nontemporal_load(&xv[tid]);
    f32x4 v1 = __builtin_nontemporal_load(&xv[tid + 256]);
    f32x4 v2 = __builtin_nontemporal_load(&xv[tid + 512]);
    const bool tail = tid < (HW4 - 768); // 16 float4 tail
    f32x4 v3;
    if (tail) v3 = __builtin_nontemporal_load(&xv[tid + 768]);

    f32x4 r0 = bspline4(v0, sc, bias);
    f32x4 r1 = bspline4(v1, sc, bias);
    f32x4 r2 = bspline4(v2, sc, bias);
    __builtin_nontemporal_store(r0, &ov[tid]);
    __builtin_nontemporal_store(r1, &ov[tid + 256]);
    __builtin_nontemporal_store(r2, &ov[tid + 512]);
    if (tail) {
        f32x4 r3 = bspline4(v3, sc, bias);
        __builtin_nontemporal_store(r3, &ov[tid + 768]);
    }
}

extern "C" void kernel_launch(void* const* d_in, const int* in_sizes, int n_in,
                              void* d_out, int out_size, void* d_ws, size_t ws_size,
                              hipStream_t stream) {
    const float* x     = (const float*)d_in[0];
    const float* coeff = (const float*)d_in[1];
    const int*   zk    = (const int*)d_in[2];
    float*       out   = (float*)d_out;

    const int n_planes = out_size / HW;  // N*C = 16384
    bspline_act_kernel<<<n_planes, 256, 0, stream>>>(x, coeff, zk, out);
}